// Round 1
// baseline (244.786 us; speedup 1.0000x reference)
//
#include <hip/hip_runtime.h>

typedef __bf16 bf16;
typedef unsigned short u16;
typedef __attribute__((ext_vector_type(8))) __bf16 bf16x8;
typedef __attribute__((ext_vector_type(16))) float f32x16;
typedef __attribute__((ext_vector_type(2))) unsigned int uint2v;
typedef __attribute__((ext_vector_type(4))) unsigned int uint4v;

#define MFMA32(a, b, c) __builtin_amdgcn_mfma_f32_32x32x16_bf16(a, b, c, 0, 0, 0)

__device__ __forceinline__ u16 bbits(float f) {
  bf16 h = (bf16)f;
  return __builtin_bit_cast(u16, h);
}
__device__ __forceinline__ float bf2f(u16 u) {
  return (float)__builtin_bit_cast(bf16, u);
}
__device__ __forceinline__ bf16x8 ldg16(const u16* p) {
  return *reinterpret_cast<const bf16x8*>(p);  // 16B-aligned by construction
}
// 8-byte-aligned LDS read of 8 bf16 as two b64s (strides are 8B-aligned, not 16B)
__device__ __forceinline__ bf16x8 ld_p8(const u16* p) {
  uint2v a = *reinterpret_cast<const uint2v*>(p);
  uint2v b = *reinterpret_cast<const uint2v*>(p + 4);
  uint4v u;
  u.x = a.x; u.y = a.y; u.z = b.x; u.w = b.y;
  return __builtin_bit_cast(bf16x8, u);
}

// ---------------------------------------------------------------------------
// Projections: A=theta(HL) -> keys Kh/Kl [b][n][64] bf16 hi/lo
//              Bm=phi(HL)  -> queries Qh/Ql [b][n][64]
//              D=g(L)      -> values V [b][c][n] bf16
// fp32 VALU matvec; x in VGPRs, weights via scalar loads (uniform addresses).
// ---------------------------------------------------------------------------
template <int CK>
__device__ __forceinline__ void matvec16(const float* x, const float* __restrict__ W,
                                         const float* __restrict__ bias, int c0, float* acc) {
#pragma unroll
  for (int cc = 0; cc < 16; ++cc) {
    float a = bias[c0 + cc];
    const float* wr = W + (c0 + cc) * CK;  // uniform -> s_load
#pragma unroll
    for (int k = 0; k < CK; ++k) a = fmaf(wr[k], x[k], a);
    acc[cc] = a;
  }
}

__global__ __launch_bounds__(256) void pa_proj(
    const float* __restrict__ H, const float* __restrict__ L,
    const float* __restrict__ tw, const float* __restrict__ tb,
    const float* __restrict__ pw, const float* __restrict__ pb,
    const float* __restrict__ gw, const float* __restrict__ gb,
    u16* __restrict__ Qh, u16* __restrict__ Ql,
    u16* __restrict__ Kh, u16* __restrict__ Kl,
    u16* __restrict__ V) {
  int p = blockIdx.x * 256 + threadIdx.x;  // 0..16383 global position
  int b = p >> 12, n = p & 4095;           // b uniform per block (16 blocks/batch)
  int g = blockIdx.y;                      // 0..11: 0-3 theta, 4-7 phi, 8-11 g
  int c0 = (g & 3) * 16;
  float acc[16];
  if (g < 8) {
    float x[128];
#pragma unroll
    for (int k = 0; k < 64; ++k) x[k] = H[(b * 64 + k) * 4096 + n];
#pragma unroll
    for (int k = 0; k < 64; ++k) x[64 + k] = L[(b * 64 + k) * 4096 + n];
    if (g < 4)
      matvec16<128>(x, tw, tb, c0, acc);
    else
      matvec16<128>(x, pw, pb, c0, acc);
    u16* hi = (g < 4) ? Kh : Qh;
    u16* lo = (g < 4) ? Kl : Ql;
    int base = p * 64 + c0;
#pragma unroll
    for (int cc = 0; cc < 16; cc += 2) {
      float a0 = acc[cc], a1 = acc[cc + 1];
      u16 h0 = bbits(a0), h1 = bbits(a1);
      u16 l0 = bbits(a0 - bf2f(h0)), l1 = bbits(a1 - bf2f(h1));
      *reinterpret_cast<unsigned*>(hi + base + cc) = (unsigned)h0 | ((unsigned)h1 << 16);
      *reinterpret_cast<unsigned*>(lo + base + cc) = (unsigned)l0 | ((unsigned)l1 << 16);
    }
  } else {
    float x[64];
#pragma unroll
    for (int k = 0; k < 64; ++k) x[k] = L[(b * 64 + k) * 4096 + n];
    matvec16<64>(x, gw, gb, c0, acc);
#pragma unroll
    for (int cc = 0; cc < 16; ++cc) V[(b * 64 + c0 + cc) * 4096 + n] = bbits(acc[cc]);
  }
}

// ---------------------------------------------------------------------------
// Prep: conv weights -> Wt[dy*3+dx][c_out][c_in] bf16; BN folded: out = A*conv+B
// ---------------------------------------------------------------------------
__global__ __launch_bounds__(256) void pa_prep(
    const float* __restrict__ cw, const float* __restrict__ cbias,
    const float* __restrict__ gamma, const float* __restrict__ beta,
    const float* __restrict__ mean, const float* __restrict__ var,
    u16* __restrict__ Wt, float* __restrict__ bnA, float* __restrict__ bnB) {
  int i = blockIdx.x * 256 + threadIdx.x;
  if (i < 36864) {
    int ci = i & 63, co = (i >> 6) & 63, s = i >> 12;  // s = dy*3+dx
    Wt[(s * 64 + co) * 64 + ci] = bbits(cw[(co * 64 + ci) * 9 + s]);
  }
  if (i < 64) {
    float rs = rsqrtf(var[i] + 1e-5f);
    float A = gamma[i] * rs;
    bnA[i] = A;
    bnB[i] = (cbias[i] - mean[i]) * A + beta[i];
  }
}

// ---------------------------------------------------------------------------
// Flash attention: O^T[c,m] = sum_n softmax_n(K[n,:]·Q[m,:]) * V[c,n]
// Block = (b, row y): m-tile 64. 4 waves split n 4-way (stride-interleaved
// 32-key tiles), private online-softmax state, merged via LDS at the end.
// mfma 32x32x16 bf16. QK in hi/lo split (3 mfma) for fp32-grade logits.
// A-frag: row=lane&31, k=(lane>>5)*8+j. B-frag: col=lane&31, k=(lane>>5)*8+j.
// C/D: col=lane&31, row=(r&3)+8*(r>>2)+4*(lane>>5).
// No __syncthreads in the K-loop (K/Q/V frags direct from global/L2; the
// only LDS use is the wave-private P C-layout->B-layout round trip).
// ---------------------------------------------------------------------------
__global__ __launch_bounds__(256, 1) void pa_flash(
    const u16* __restrict__ Qh, const u16* __restrict__ Ql,
    const u16* __restrict__ Kh, const u16* __restrict__ Kl,
    const u16* __restrict__ V, u16* __restrict__ E) {
  __shared__ u16 Pbuf[4][64 * 36];  // per-wave P, row stride 36 (2-way banks, 8B aligned)
  __shared__ float Obuf[64 * 67];   // merge buffer [c][m], stride 67
  __shared__ float MLm[4][2][32];
  __shared__ float MLl[4][2][32];
  __shared__ float Lstar[64];

  int tid = threadIdx.x;
  int w = tid >> 6, lane = tid & 63;
  int l31 = lane & 31, q2 = lane >> 5;
  int blk = blockIdx.x;
  int b = blk >> 6, y = blk & 63;
  int m0 = y * 64;
  int bq = b * 4096;

  // Q fragments (held in registers for the whole kernel): B-operand layout
  bf16x8 qh[2][4], ql[2][4];
#pragma unroll
  for (int mb = 0; mb < 2; ++mb)
#pragma unroll
    for (int kc = 0; kc < 4; ++kc) {
      int idx = (bq + m0 + mb * 32 + l31) * 64 + kc * 16 + q2 * 8;
      qh[mb][kc] = ldg16(Qh + idx);
      ql[mb][kc] = ldg16(Ql + idx);
    }

  f32x16 accO[2][2] = {};          // [cb][mb], C layout: row=c, col=m
  float Mm[2] = {-1e30f, -1e30f};  // running max per m-column (mb 0/1)
  float Ll[2] = {0.f, 0.f};        // running sum
  u16* mypb = &Pbuf[w][0];

#pragma unroll 1
  for (int it = 0; it < 32; ++it) {
    int n0 = it * 128 + w * 32;  // this wave's 32-key tile

    bf16x8 kh[4], kl[4];
#pragma unroll
    for (int kc = 0; kc < 4; ++kc) {
      int idx = (bq + n0 + l31) * 64 + kc * 16 + q2 * 8;
      kh[kc] = ldg16(Kh + idx);
      kl[kc] = ldg16(Kl + idx);
    }
    bf16x8 vf[2][2];
#pragma unroll
    for (int cbi = 0; cbi < 2; ++cbi)
#pragma unroll
      for (int kch = 0; kch < 2; ++kch)
        vf[cbi][kch] = ldg16(V + (b * 64 + cbi * 32 + l31) * 4096 + n0 + kch * 16 + q2 * 8);

    // S^T = K · Q^T with hi/lo split (drop kl*ql); two partial accs -> depth-6 chains
    f32x16 sA[2], sB[2];
#pragma unroll
    for (int mb = 0; mb < 2; ++mb) {
      f32x16 a = {};
      f32x16 b2 = {};
#pragma unroll
      for (int kc = 0; kc < 2; ++kc) {
        a = MFMA32(kh[kc], qh[mb][kc], a);
        a = MFMA32(kh[kc], ql[mb][kc], a);
        a = MFMA32(kl[kc], qh[mb][kc], a);
      }
#pragma unroll
      for (int kc = 2; kc < 4; ++kc) {
        b2 = MFMA32(kh[kc], qh[mb][kc], b2);
        b2 = MFMA32(kh[kc], ql[mb][kc], b2);
        b2 = MFMA32(kl[kc], qh[mb][kc], b2);
      }
      sA[mb] = a;
      sB[mb] = b2;
    }

    // online softmax (per m-column; lane holds 16 of the 32 n's, partner via xor-32)
#pragma unroll
    for (int mb = 0; mb < 2; ++mb) {
      float s[16];
#pragma unroll
      for (int r = 0; r < 16; ++r) s[r] = sA[mb][r] + sB[mb][r];
      float tmax = s[0];
#pragma unroll
      for (int r = 1; r < 16; ++r) tmax = fmaxf(tmax, s[r]);
      tmax = fmaxf(tmax, __shfl_xor(tmax, 32, 64));
      float newM = fmaxf(Mm[mb], tmax);
      float alpha = __expf(Mm[mb] - newM);
      Mm[mb] = newM;
      float pv[16];
      float psum = 0.f;
#pragma unroll
      for (int r = 0; r < 16; ++r) {
        pv[r] = __expf(s[r] - newM);
        psum += pv[r];
      }
      psum += __shfl_xor(psum, 32, 64);
      Ll[mb] = Ll[mb] * alpha + psum;
#pragma unroll
      for (int r = 0; r < 16; ++r) {
        accO[0][mb][r] *= alpha;
        accO[1][mb][r] *= alpha;
      }
      // P: C-layout regs -> LDS [m][n] (B-operand layout for PV). 4 consec n per reg-quad.
      u16* prow = mypb + (mb * 32 + l31) * 36;
#pragma unroll
      for (int rq = 0; rq < 4; ++rq) {
        unsigned lo = (unsigned)bbits(pv[rq * 4 + 0]) | ((unsigned)bbits(pv[rq * 4 + 1]) << 16);
        unsigned hi = (unsigned)bbits(pv[rq * 4 + 2]) | ((unsigned)bbits(pv[rq * 4 + 3]) << 16);
        uint2v uu;
        uu.x = lo;
        uu.y = hi;
        *reinterpret_cast<uint2v*>(prow + rq * 8 + q2 * 4) = uu;  // n = 8*rq + 4*q2 + 0..3
      }
    }

    // PV: O^T += V^T(A) · P^T(B)
#pragma unroll
    for (int mb = 0; mb < 2; ++mb) {
      const u16* prow = mypb + (mb * 32 + l31) * 36;
      bf16x8 p0 = ld_p8(prow + q2 * 8);       // k = n 0..15
      bf16x8 p1 = ld_p8(prow + 16 + q2 * 8);  // k = n 16..31
      accO[0][mb] = MFMA32(vf[0][0], p0, accO[0][mb]);
      accO[0][mb] = MFMA32(vf[0][1], p1, accO[0][mb]);
      accO[1][mb] = MFMA32(vf[1][0], p0, accO[1][mb]);
      accO[1][mb] = MFMA32(vf[1][1], p1, accO[1][mb]);
    }
  }

  // ---- merge the 4 waves' partial (O, M, l) ----
  if (q2 == 0) {
#pragma unroll
    for (int mb = 0; mb < 2; ++mb) {
      MLm[w][mb][l31] = Mm[mb];
      MLl[w][mb][l31] = Ll[mb];
    }
  }
  __syncthreads();
  float mysc[2];
#pragma unroll
  for (int mb = 0; mb < 2; ++mb) {
    float M = MLm[0][mb][l31];
    for (int ww = 1; ww < 4; ++ww) M = fmaxf(M, MLm[ww][mb][l31]);
    float ls = 0.f;
    for (int ww = 0; ww < 4; ++ww) ls += MLl[ww][mb][l31] * __expf(MLm[ww][mb][l31] - M);
    mysc[mb] = __expf(Mm[mb] - M);
    if (w == 0 && q2 == 0) Lstar[mb * 32 + l31] = ls;
  }
  for (int ww = 0; ww < 4; ++ww) {
    if (w == ww) {
#pragma unroll
      for (int cbi = 0; cbi < 2; ++cbi)
#pragma unroll
        for (int mb = 0; mb < 2; ++mb) {
          float sc = mysc[mb];
#pragma unroll
          for (int r = 0; r < 16; ++r) {
            int c = cbi * 32 + (r & 3) + 8 * (r >> 2) + 4 * q2;
            int m = mb * 32 + l31;
            float* dst = &Obuf[c * 67 + m];
            float v = accO[cbi][mb][r] * sc;
            if (ww == 0)
              *dst = v;
            else
              *dst += v;
          }
        }
    }
    __syncthreads();
  }
  // write E[b][m][c] bf16 (spatial-major for the conv's B-operand)
  int em = tid >> 2, ec0 = (tid & 3) * 16;
  float invl = 1.0f / Lstar[em];
  float vals[16];
#pragma unroll
  for (int j = 0; j < 16; ++j) vals[j] = Obuf[(ec0 + j) * 67 + em] * invl;
  uint4v u0, u1;
  u0.x = (unsigned)bbits(vals[0]) | ((unsigned)bbits(vals[1]) << 16);
  u0.y = (unsigned)bbits(vals[2]) | ((unsigned)bbits(vals[3]) << 16);
  u0.z = (unsigned)bbits(vals[4]) | ((unsigned)bbits(vals[5]) << 16);
  u0.w = (unsigned)bbits(vals[6]) | ((unsigned)bbits(vals[7]) << 16);
  u1.x = (unsigned)bbits(vals[8]) | ((unsigned)bbits(vals[9]) << 16);
  u1.y = (unsigned)bbits(vals[10]) | ((unsigned)bbits(vals[11]) << 16);
  u1.z = (unsigned)bbits(vals[12]) | ((unsigned)bbits(vals[13]) << 16);
  u1.w = (unsigned)bbits(vals[14]) | ((unsigned)bbits(vals[15]) << 16);
  u16* ep = E + (bq + m0 + em) * 64 + ec0;
  *reinterpret_cast<uint4v*>(ep) = u0;
  *reinterpret_cast<uint4v*>(ep + 8) = u1;
}

// ---------------------------------------------------------------------------
// Conv3x3(SAME)+BN+ReLU+residual as 9 shifted MFMA GEMMs.
// Block = (b, row y). LDS holds rows y-1..y+1 with x-halo, [x+1][c] stride 68.
// ---------------------------------------------------------------------------
__global__ __launch_bounds__(256) void pa_conv(
    const u16* __restrict__ E, const u16* __restrict__ Wt,
    const float* __restrict__ bnA, const float* __restrict__ bnB,
    const float* __restrict__ H, float* __restrict__ out) {
  __shared__ u16 Er[3][66 * 68];
  int tid = threadIdx.x;
  int blk = blockIdx.x;
  int b = blk >> 6, y = blk & 63;
  int lane = tid & 63;
  int l31 = lane & 31, q2 = lane >> 5;
  int wv = tid >> 6;
  int cbi = wv >> 1, mb = wv & 1;
  int s0 = (y == 0) ? 1 : 0;
  int s1 = (y == 63) ? 1 : 2;

  for (int s = s0; s <= s1; ++s) {
    int yy = y + s - 1;
#pragma unroll
    for (int rep = 0; rep < 2; ++rep) {
      int id = rep * 256 + tid;
      int x = id >> 3, co = (id & 7) * 8;
      const uint2v* src = reinterpret_cast<const uint2v*>(E + ((b * 4096 + yy * 64 + x) * 64 + co));
      uint2v a = src[0], b4 = src[1];
      u16* d = &Er[s][(x + 1) * 68 + co];
      *reinterpret_cast<uint2v*>(d) = a;
      *reinterpret_cast<uint2v*>(d + 4) = b4;
    }
  }
  if (tid < 96) {  // zero x-halo columns
    int s = tid >> 5, side = (tid >> 4) & 1, co = (tid & 15) * 4;
    uint2v z;
    z.x = 0;
    z.y = 0;
    *reinterpret_cast<uint2v*>(&Er[s][(side ? 65 : 0) * 68 + co]) = z;
  }
  __syncthreads();

  f32x16 acc = {};
  for (int s = s0; s <= s1; ++s) {
#pragma unroll
    for (int dx = 0; dx < 3; ++dx)
#pragma unroll
      for (int kc = 0; kc < 4; ++kc) {
        bf16x8 a = ldg16(Wt + ((s * 3 + dx) * 64 + cbi * 32 + l31) * 64 + kc * 16 + q2 * 8);
        const u16* pbr = &Er[s][(mb * 32 + l31 + dx) * 68 + kc * 16 + q2 * 8];
        bf16x8 bb = ld_p8(pbr);
        acc = MFMA32(a, bb, acc);
      }
  }
#pragma unroll
  for (int r = 0; r < 16; ++r) {
    int c = cbi * 32 + (r & 3) + 8 * (r >> 2) + 4 * q2;
    int x = mb * 32 + l31;
    float v = acc[r] * bnA[c] + bnB[c];
    v = fmaxf(v, 0.f);
    int idx = ((b * 64 + c) * 64 + y) * 64 + x;
    out[idx] = H[idx] + v;
  }
}

// ---------------------------------------------------------------------------
extern "C" void kernel_launch(void* const* d_in, const int* in_sizes, int n_in,
                              void* d_out, int out_size, void* d_ws, size_t ws_size,
                              hipStream_t stream) {
  (void)in_sizes; (void)n_in; (void)out_size; (void)ws_size;
  const float* H = (const float*)d_in[0];
  const float* L = (const float*)d_in[1];
  const float* tw = (const float*)d_in[2];
  const float* tb = (const float*)d_in[3];
  const float* pw = (const float*)d_in[4];
  const float* pb = (const float*)d_in[5];
  const float* gw = (const float*)d_in[6];
  const float* gb = (const float*)d_in[7];
  const float* cw = (const float*)d_in[8];
  const float* cb = (const float*)d_in[9];
  const float* gamma = (const float*)d_in[10];
  const float* beta = (const float*)d_in[11];
  const float* mean = (const float*)d_in[12];
  const float* var = (const float*)d_in[13];

  const int NC = 16384 * 64;  // 1M elements per [b][n][c] plane
  u16* Qh = (u16*)d_ws;
  u16* Ql = Qh + NC;
  u16* Kh = Ql + NC;
  u16* Kl = Kh + NC;
  u16* Vv = Kl + NC;
  u16* Eb = Vv + NC;
  u16* Wt = Eb + NC;
  float* bnA = (float*)(Wt + 36864);
  float* bnB = bnA + 64;

  pa_proj<<<dim3(64, 12), 256, 0, stream>>>(H, L, tw, tb, pw, pb, gw, gb, Qh, Ql, Kh, Kl, Vv);
  pa_prep<<<144, 256, 0, stream>>>(cw, cb, gamma, beta, mean, var, Wt, bnA, bnB);
  pa_flash<<<256, 256, 0, stream>>>(Qh, Ql, Kh, Kl, Vv, Eb);
  pa_conv<<<256, 256, 0, stream>>>(Eb, Wt, bnA, bnB, H, (float*)d_out);
}